// Round 9
// baseline (612.814 us; speedup 1.0000x reference)
//
#include <hip/hip_runtime.h>
#include <hip/hip_bf16.h>

#define HID 128
#define NEG 0.2f
#define LN_EPS 1e-5f
#define NG 16

static __device__ __forceinline__ float leaky(float x) { return x > 0.f ? x : NEG * x; }

static __device__ __forceinline__ unsigned pack_bf2(float a, float b) {
  __hip_bfloat16 ha = __float2bfloat16(a), hb = __float2bfloat16(b);
  unsigned ua = *reinterpret_cast<unsigned short*>(&ha);
  unsigned ub = *reinterpret_cast<unsigned short*>(&hb);
  return ua | (ub << 16);
}

// ---------------- CSR build ----------------
__global__ __launch_bounds__(256) void k_edge_count(const int* __restrict__ ei, int E,
                                                    int* __restrict__ deg) {
  for (int e = blockIdx.x * blockDim.x + threadIdx.x; e < E; e += gridDim.x * blockDim.x)
    atomicAdd(&deg[ei[E + e]], 1);
}

__global__ __launch_bounds__(1024) void k_scan_a(const int* __restrict__ deg, int* __restrict__ offs,
                                                 int* __restrict__ part, int N) {
  __shared__ int s[1024];
  int i = blockIdx.x * 1024 + threadIdx.x;
  int v = (i < N) ? deg[i] : 0;
  s[threadIdx.x] = v;
  __syncthreads();
  for (int d = 1; d < 1024; d <<= 1) {
    int t = (threadIdx.x >= d) ? s[threadIdx.x - d] : 0;
    __syncthreads();
    s[threadIdx.x] += t;
    __syncthreads();
  }
  if (i < N) offs[i + 1] = s[threadIdx.x];
  if (threadIdx.x == 1023) part[blockIdx.x] = s[1023];
}

__global__ __launch_bounds__(1024) void k_scan_b(int* __restrict__ part, int nb) {
  __shared__ int s[1024];
  int v = (threadIdx.x < nb) ? part[threadIdx.x] : 0;
  s[threadIdx.x] = v;
  __syncthreads();
  for (int d = 1; d < 1024; d <<= 1) {
    int t = (threadIdx.x >= d) ? s[threadIdx.x - d] : 0;
    __syncthreads();
    s[threadIdx.x] += t;
    __syncthreads();
  }
  if (threadIdx.x < nb) part[threadIdx.x] = (threadIdx.x == 0) ? 0 : s[threadIdx.x - 1];
}

__global__ __launch_bounds__(256) void k_scan_c(int* __restrict__ offs, const int* __restrict__ part, int N) {
  int i = blockIdx.x * blockDim.x + threadIdx.x;
  if (i < N) offs[i + 1] += part[i >> 10];
  if (i == 0) offs[0] = 0;
}

__global__ __launch_bounds__(256) void k_edge_fill(const int* __restrict__ ei, int E,
                                                   const int* __restrict__ offs,
                                                   int* __restrict__ cursor, int* __restrict__ csr) {
  for (int e = blockIdx.x * blockDim.x + threadIdx.x; e < E; e += gridDim.x * blockDim.x) {
    int d = ei[E + e];
    int slot = atomicAdd(&cursor[d], 1);
    csr[offs[d] + slot] = ei[e];
  }
}

// ---------------- tiled GEMM: h(bf16) = x @ W ; as/ad reduced in-wave ----------------
__global__ __launch_bounds__(512) void k_gemm(const float* __restrict__ xin, int xstride,
                                              const float* __restrict__ W,
                                              const float* __restrict__ a_s, const float* __restrict__ a_d,
                                              unsigned* __restrict__ hbf, float* __restrict__ as_out,
                                              float* __restrict__ ad_out, int N, int ntiles) {
  __shared__ float Ws[HID * HID];   // 64 KB
  __shared__ float xs[32][HID];     // 16 KB
  int t = threadIdx.x;
  for (int i = t * 4; i < HID * HID; i += 2048) *(float4*)&Ws[i] = *(const float4*)&W[i];
  int rq = t >> 6, pr = t & 63;
  int c2 = pr * 2;
  float a_s0 = a_s[c2], a_s1 = a_s[c2 + 1], a_d0 = a_d[c2], a_d1 = a_d[c2 + 1];
  for (int tile = blockIdx.x; tile < ntiles; tile += gridDim.x) {
    int r0 = tile * 32;
    __syncthreads();
#pragma unroll
    for (int i = 0; i < 2; ++i) {
      int idx = i * 512 + t;
      int r = idx >> 5, q = idx & 31;
      float4 v = make_float4(0.f, 0.f, 0.f, 0.f);
      if (r0 + r < N) v = *(const float4*)&xin[(size_t)(r0 + r) * xstride + q * 4];
      *(float4*)&xs[r][q * 4] = v;
    }
    __syncthreads();
    float acc[4][2];
#pragma unroll
    for (int r = 0; r < 4; ++r) { acc[r][0] = 0.f; acc[r][1] = 0.f; }
    for (int k0 = 0; k0 < HID; k0 += 4) {
      float2 w0 = *(const float2*)&Ws[(k0 + 0) * HID + c2];
      float2 w1 = *(const float2*)&Ws[(k0 + 1) * HID + c2];
      float2 w2 = *(const float2*)&Ws[(k0 + 2) * HID + c2];
      float2 w3 = *(const float2*)&Ws[(k0 + 3) * HID + c2];
#pragma unroll
      for (int r = 0; r < 4; ++r) {
        float4 xv = *(const float4*)&xs[rq * 4 + r][k0];
        acc[r][0] = fmaf(xv.x, w0.x, acc[r][0]);
        acc[r][1] = fmaf(xv.x, w0.y, acc[r][1]);
        acc[r][0] = fmaf(xv.y, w1.x, acc[r][0]);
        acc[r][1] = fmaf(xv.y, w1.y, acc[r][1]);
        acc[r][0] = fmaf(xv.z, w2.x, acc[r][0]);
        acc[r][1] = fmaf(xv.z, w2.y, acc[r][1]);
        acc[r][0] = fmaf(xv.w, w3.x, acc[r][0]);
        acc[r][1] = fmaf(xv.w, w3.y, acc[r][1]);
      }
    }
#pragma unroll
    for (int r = 0; r < 4; ++r) {
      int row = r0 + rq * 4 + r;
      float ps = acc[r][0] * a_s0 + acc[r][1] * a_s1;
      float pd = acc[r][0] * a_d0 + acc[r][1] * a_d1;
#pragma unroll
      for (int msk = 1; msk < 16; msk <<= 1) {
        ps += __shfl_xor(ps, msk);
        pd += __shfl_xor(pd, msk);
      }
      if (row < N) {
        hbf[(size_t)row * 64 + pr] = pack_bf2(acc[r][0], acc[r][1]);
        if ((pr & 15) == 0) {
          as_out[row * 4 + (pr >> 4)] = ps;
          ad_out[row * 4 + (pr >> 4)] = pd;
        }
      }
    }
  }
}

// ---------------- per-edge softmax numerators, CSR-positional ----------------
__global__ __launch_bounds__(256) void k_escore(const int* __restrict__ offs, const int* __restrict__ csr,
                                                const float* __restrict__ as, const float* __restrict__ ad,
                                                float* __restrict__ pcs, int N) {
  int wave = threadIdx.x >> 6, lane = threadIdx.x & 63;
  int dst = blockIdx.x * 4 + wave;
  if (dst >= N) return;
  const float4 ad4 = *(const float4*)&ad[dst * 4];
  int beg = offs[dst], end = offs[dst + 1];
  for (int i = beg + lane; i < end; i += 64) {
    int s = csr[i];
    float4 a4 = *(const float4*)&as[s * 4];
    float4 p;
    p.x = __expf(leaky(a4.x + ad4.x));
    p.y = __expf(leaky(a4.y + ad4.y));
    p.z = __expf(leaky(a4.z + ad4.z));
    p.w = __expf(leaky(a4.w + ad4.w));
    *(float4*)&pcs[(size_t)i * 4] = p;
  }
}

// ---------------- per-dst agg+LN+ELU: wave/dst, dual-bank D=4 pipeline ----------------
// lane = g*16+q : g = edge slot (4 edges/j-iter), q = channel block (8 ch), head = q>>2
__global__ __launch_bounds__(256) void k_gat_agg(const int* __restrict__ offs, const int* __restrict__ csr,
                                                 const float* __restrict__ pcs,
                                                 const float* __restrict__ as, const float* __restrict__ ad,
                                                 const uint4* __restrict__ hb, const float* __restrict__ bias,
                                                 const float* __restrict__ gam, const float* __restrict__ bet,
                                                 float* __restrict__ out, int ostride, int N) {
  int wave = threadIdx.x >> 6, lane = threadIdx.x & 63;
  int dst = blockIdx.x * 4 + wave;
  if (dst >= N) return;
  int q = lane & 15, g = lane >> 4, head = q >> 2;
  float p_self = __expf(leaky(as[dst * 4 + head] + ad[dst * 4 + head]));
  float acc[8];
#pragma unroll
  for (int k = 0; k < 8; ++k) acc[k] = 0.f;
  float ssum = 0.f;
  int beg = offs[dst], end = offs[dst + 1];

#define LOADB(H, P, j0)                                            \
  {                                                                \
    _Pragma("unroll") for (int d = 0; d < 4; ++d) {                \
      int sel = ((j0) + d) * 4 + g;                                \
      int s = __shfl(my, sel & 63);                                \
      bool v = sel < cnt;                                          \
      int ss = v ? s : 0;                                          \
      int pos = v ? (base + sel) : beg;                            \
      float pv = pcs[(size_t)pos * 4 + head];                      \
      P[d] = v ? pv : 0.f;                                         \
      H[d] = hb[(size_t)ss * 16 + q];                              \
    }                                                              \
  }
#define CONSB(H, P)                                                \
  {                                                                \
    _Pragma("unroll") for (int d = 0; d < 4; ++d) {                \
      float p = P[d];                                              \
      ssum += p;                                                   \
      _Pragma("unroll") for (int k = 0; k < 4; ++k) {              \
        unsigned u = (&H[d].x)[k];                                 \
        acc[2 * k]     = fmaf(p, __uint_as_float(u << 16), acc[2 * k]);          \
        acc[2 * k + 1] = fmaf(p, __uint_as_float(u & 0xffff0000u), acc[2 * k + 1]); \
      }                                                            \
    }                                                              \
  }

  for (int base = beg; base < end; base += 64) {
    int idx = base + lane;
    int my = (idx < end) ? csr[idx] : 0;
    int cnt = min(64, end - base);
    int njj = (cnt + 3) >> 2;
    uint4 hA[4], hB[4];
    float pA[4], pB[4];
    LOADB(hA, pA, 0)
    for (int jb = 0; jb < njj; jb += 8) {
      LOADB(hB, pB, jb + 4)
      CONSB(hA, pA)
      LOADB(hA, pA, jb + 8)
      CONSB(hB, pB)
    }
  }
#undef LOADB
#undef CONSB

  // combine the 4 edge groups (bits 4,5)
#pragma unroll
  for (int k = 0; k < 8; ++k) {
    acc[k] += __shfl_xor(acc[k], 16);
    acc[k] += __shfl_xor(acc[k], 32);
  }
  // denom: sum over bits {0,1,4,5}; each (edge,head) counted 4x -> *0.25
  float red = ssum;
  red += __shfl_xor(red, 1);
  red += __shfl_xor(red, 2);
  red += __shfl_xor(red, 16);
  red += __shfl_xor(red, 32);
  float denom = 0.25f * red + p_self;
  // self-loop
  uint4 hd = hb[(size_t)dst * 16 + q];
#pragma unroll
  for (int k = 0; k < 4; ++k) {
    unsigned u = (&hd.x)[k];
    acc[2 * k]     = fmaf(p_self, __uint_as_float(u << 16), acc[2 * k]);
    acc[2 * k + 1] = fmaf(p_self, __uint_as_float(u & 0xffff0000u), acc[2 * k + 1]);
  }
  // normalize + bias
  int cb = q * 8;
  float inv = 1.f / denom;
  float val[8], part = 0.f;
#pragma unroll
  for (int k = 0; k < 8; ++k) {
    val[k] = acc[k] * inv + bias[cb + k];
    part += val[k];
  }
  // LayerNorm: reduce over q (bits 0..3)
  part += __shfl_xor(part, 1);
  part += __shfl_xor(part, 2);
  part += __shfl_xor(part, 4);
  part += __shfl_xor(part, 8);
  float mu = part * (1.f / HID);
  float vpart = 0.f;
#pragma unroll
  for (int k = 0; k < 8; ++k) {
    val[k] -= mu;
    vpart += val[k] * val[k];
  }
  vpart += __shfl_xor(vpart, 1);
  vpart += __shfl_xor(vpart, 2);
  vpart += __shfl_xor(vpart, 4);
  vpart += __shfl_xor(vpart, 8);
  float rstd = rsqrtf(vpart * (1.f / HID) + LN_EPS);
  float y[8];
#pragma unroll
  for (int k = 0; k < 8; ++k) {
    float tv = val[k] * rstd * gam[cb + k] + bet[cb + k];
    y[k] = tv > 0.f ? tv : expm1f(tv);
  }
  if (g == 0) {
    *(float4*)&out[(size_t)dst * ostride + cb]     = make_float4(y[0], y[1], y[2], y[3]);
    *(float4*)&out[(size_t)dst * ostride + cb + 4] = make_float4(y[4], y[5], y[6], y[7]);
  }
}

// ---------------- per-graph mean readout (reads strided x) ----------------
__global__ __launch_bounds__(256) void k_graph_sum(const float* __restrict__ x, int xstride,
                                                   const int* __restrict__ bat,
                                                   float* __restrict__ gsum, float* __restrict__ gcnt, int N) {
  __shared__ float ls[NG * HID];
  __shared__ float lc[NG];
  for (int i = threadIdx.x; i < NG * HID; i += 256) ls[i] = 0.f;
  if (threadIdx.x < NG) lc[threadIdx.x] = 0.f;
  __syncthreads();
  int wave = threadIdx.x >> 6, lane = threadIdx.x & 63;
  for (int n = blockIdx.x * 4 + wave; n < N; n += gridDim.x * 4) {
    int b = bat[n];
    float2 v = *(const float2*)&x[(size_t)n * xstride + lane * 2];
    atomicAdd(&ls[b * HID + lane * 2], v.x);
    atomicAdd(&ls[b * HID + lane * 2 + 1], v.y);
    if (lane == 0) atomicAdd(&lc[b], 1.f);
  }
  __syncthreads();
  for (int i = threadIdx.x; i < NG * HID; i += 256) atomicAdd(&gsum[i], ls[i]);
  if (threadIdx.x < NG) atomicAdd(&gcnt[threadIdx.x], lc[threadIdx.x]);
}

// g-half of output
__global__ __launch_bounds__(256) void k_gout(const int* __restrict__ bat, const float* __restrict__ gsum,
                                              const float* __restrict__ gcnt, float* __restrict__ out, int N) {
  int total = N * 32;
  for (int idx = blockIdx.x * blockDim.x + threadIdx.x; idx < total; idx += gridDim.x * blockDim.x) {
    int n = idx >> 5, qq = idx & 31;
    int b = bat[n];
    float rin = 1.f / fmaxf(gcnt[b], 1.f);
    float4 gv = *(const float4*)&gsum[b * HID + qq * 4];
    *(float4*)&out[(size_t)n * 256 + 128 + qq * 4] =
        make_float4(gv.x * rin, gv.y * rin, gv.z * rin, gv.w * rin);
  }
}

extern "C" void kernel_launch(void* const* d_in, const int* in_sizes, int n_in,
                              void* d_out, int out_size, void* d_ws, size_t ws_size,
                              hipStream_t stream) {
  const float* x   = (const float*)d_in[0];
  const int*   ei  = (const int*)d_in[1];
  const int*   bat = (const int*)d_in[2];
  const float* W1  = (const float*)d_in[3];
  const float* as1 = (const float*)d_in[4];
  const float* ad1 = (const float*)d_in[5];
  const float* b1  = (const float*)d_in[6];
  const float* g1  = (const float*)d_in[7];
  const float* be1 = (const float*)d_in[8];
  const float* W2  = (const float*)d_in[9];
  const float* as2 = (const float*)d_in[10];
  const float* ad2 = (const float*)d_in[11];
  const float* b2  = (const float*)d_in[12];
  const float* g2  = (const float*)d_in[13];
  const float* be2 = (const float*)d_in[14];
  int N = in_sizes[0] / HID;
  int E = in_sizes[1] / 2;

  char* p = (char*)d_ws;
  auto alloc = [&](size_t bytes) {
    void* r = (void*)p;
    p += (bytes + 255) & ~(size_t)255;
    return r;
  };
  int*      deg  = (int*)alloc((size_t)N * 4);   // also fill cursor
  int*      offs = (int*)alloc((size_t)(N + 1) * 4);
  int       nsb  = (N + 1023) / 1024;
  int*      part = (int*)alloc((size_t)nsb * 4);
  int*      csr  = (int*)alloc((size_t)E * 4);
  unsigned* hbf  = (unsigned*)alloc((size_t)N * 64 * 4);   // bf16x2-packed h
  float*    asb  = (float*)alloc((size_t)N * 4 * 4);
  float*    adb  = (float*)alloc((size_t)N * 4 * 4);
  float*    pcs  = (float*)alloc((size_t)E * 4 * 4);       // per-edge exp'd logits
  float*    gsum = (float*)alloc((size_t)NG * HID * 4);
  float*    gcnt = (float*)alloc((size_t)NG * 4);

  hipMemsetAsync(deg, 0, (size_t)N * 4, stream);
  hipMemsetAsync(gsum, 0, (size_t)NG * HID * 4, stream);
  hipMemsetAsync(gcnt, 0, (size_t)NG * 4, stream);

  int egrid = (E + 255) / 256;
  if (egrid > 2048) egrid = 2048;
  k_edge_count<<<egrid, 256, 0, stream>>>(ei, E, deg);
  k_scan_a<<<nsb, 1024, 0, stream>>>(deg, offs, part, N);
  k_scan_b<<<1, 1024, 0, stream>>>(part, nsb);
  k_scan_c<<<(N + 255) / 256, 256, 0, stream>>>(offs, part, N);
  hipMemsetAsync(deg, 0, (size_t)N * 4, stream);  // cursor
  k_edge_fill<<<egrid, 256, 0, stream>>>(ei, E, offs, deg, csr);

  int ntiles = (N + 31) / 32;
  int ggrid = ntiles < 512 ? ntiles : 512;
  int agrid = (N + 3) / 4;
  float* xhalf = (float*)d_out;  // layer outputs live in d_out's x-half (stride 256)

  k_gemm<<<ggrid, 512, 0, stream>>>(x, HID, W1, as1, ad1, hbf, asb, adb, N, ntiles);
  k_escore<<<agrid, 256, 0, stream>>>(offs, csr, asb, adb, pcs, N);
  k_gat_agg<<<agrid, 256, 0, stream>>>(offs, csr, pcs, asb, adb, (const uint4*)hbf, b1, g1, be1,
                                       xhalf, 256, N);
  k_gemm<<<ggrid, 512, 0, stream>>>(xhalf, 256, W2, as2, ad2, hbf, asb, adb, N, ntiles);
  k_escore<<<agrid, 256, 0, stream>>>(offs, csr, asb, adb, pcs, N);
  k_gat_agg<<<agrid, 256, 0, stream>>>(offs, csr, pcs, asb, adb, (const uint4*)hbf, b2, g2, be2,
                                       xhalf, 256, N);

  k_graph_sum<<<256, 256, 0, stream>>>(xhalf, 256, bat, gsum, gcnt, N);
  int ogrid = (N * 32 + 255) / 256;
  if (ogrid > 4096) ogrid = 4096;
  k_gout<<<ogrid, 256, 0, stream>>>(bat, gsum, gcnt, (float*)d_out, N);
}

// Round 10
// 582.351 us; speedup vs baseline: 1.0523x; 1.0523x over previous
//
#include <hip/hip_runtime.h>
#include <hip/hip_bf16.h>

#define HID 128
#define NEG 0.2f
#define LN_EPS 1e-5f
#define NG 16

static __device__ __forceinline__ float leaky(float x) { return x > 0.f ? x : NEG * x; }

static __device__ __forceinline__ unsigned pack_bf2(float a, float b) {
  __hip_bfloat16 ha = __float2bfloat16(a), hb = __float2bfloat16(b);
  unsigned ua = *reinterpret_cast<unsigned short*>(&ha);
  unsigned ub = *reinterpret_cast<unsigned short*>(&hb);
  return ua | (ub << 16);
}

// ---------------- CSR build ----------------
__global__ __launch_bounds__(256) void k_edge_count(const int* __restrict__ ei, int E,
                                                    int* __restrict__ deg) {
  for (int e = blockIdx.x * blockDim.x + threadIdx.x; e < E; e += gridDim.x * blockDim.x)
    atomicAdd(&deg[ei[E + e]], 1);
}

__global__ __launch_bounds__(1024) void k_scan_a(const int* __restrict__ deg, int* __restrict__ offs,
                                                 int* __restrict__ part, int N) {
  __shared__ int s[1024];
  int i = blockIdx.x * 1024 + threadIdx.x;
  int v = (i < N) ? deg[i] : 0;
  s[threadIdx.x] = v;
  __syncthreads();
  for (int d = 1; d < 1024; d <<= 1) {
    int t = (threadIdx.x >= d) ? s[threadIdx.x - d] : 0;
    __syncthreads();
    s[threadIdx.x] += t;
    __syncthreads();
  }
  if (i < N) offs[i + 1] = s[threadIdx.x];
  if (threadIdx.x == 1023) part[blockIdx.x] = s[1023];
}

__global__ __launch_bounds__(1024) void k_scan_b(int* __restrict__ part, int nb) {
  __shared__ int s[1024];
  int v = (threadIdx.x < nb) ? part[threadIdx.x] : 0;
  s[threadIdx.x] = v;
  __syncthreads();
  for (int d = 1; d < 1024; d <<= 1) {
    int t = (threadIdx.x >= d) ? s[threadIdx.x - d] : 0;
    __syncthreads();
    s[threadIdx.x] += t;
    __syncthreads();
  }
  if (threadIdx.x < nb) part[threadIdx.x] = (threadIdx.x == 0) ? 0 : s[threadIdx.x - 1];
}

__global__ __launch_bounds__(256) void k_scan_c(int* __restrict__ offs, const int* __restrict__ part, int N) {
  int i = blockIdx.x * blockDim.x + threadIdx.x;
  if (i < N) offs[i + 1] += part[i >> 10];
  if (i == 0) offs[0] = 0;
}

__global__ __launch_bounds__(256) void k_edge_fill(const int* __restrict__ ei, int E,
                                                   const int* __restrict__ offs,
                                                   int* __restrict__ cursor, int* __restrict__ csr) {
  for (int e = blockIdx.x * blockDim.x + threadIdx.x; e < E; e += gridDim.x * blockDim.x) {
    int d = ei[E + e];
    int slot = atomicAdd(&cursor[d], 1);
    csr[offs[d] + slot] = ei[e];
  }
}

// ---------------- tiled GEMM: h(bf16) = x @ W ; as/ad reduced in-wave ----------------
__global__ __launch_bounds__(512) void k_gemm(const float* __restrict__ xin, int xstride,
                                              const float* __restrict__ W,
                                              const float* __restrict__ a_s, const float* __restrict__ a_d,
                                              unsigned* __restrict__ hbf, float* __restrict__ as_out,
                                              float* __restrict__ ad_out, int N, int ntiles) {
  __shared__ float Ws[HID * HID];   // 64 KB
  __shared__ float xs[32][HID];     // 16 KB
  int t = threadIdx.x;
  for (int i = t * 4; i < HID * HID; i += 2048) *(float4*)&Ws[i] = *(const float4*)&W[i];
  int rq = t >> 6, pr = t & 63;
  int c2 = pr * 2;
  float a_s0 = a_s[c2], a_s1 = a_s[c2 + 1], a_d0 = a_d[c2], a_d1 = a_d[c2 + 1];
  for (int tile = blockIdx.x; tile < ntiles; tile += gridDim.x) {
    int r0 = tile * 32;
    __syncthreads();
#pragma unroll
    for (int i = 0; i < 2; ++i) {
      int idx = i * 512 + t;
      int r = idx >> 5, q = idx & 31;
      float4 v = make_float4(0.f, 0.f, 0.f, 0.f);
      if (r0 + r < N) v = *(const float4*)&xin[(size_t)(r0 + r) * xstride + q * 4];
      *(float4*)&xs[r][q * 4] = v;
    }
    __syncthreads();
    float acc[4][2];
#pragma unroll
    for (int r = 0; r < 4; ++r) { acc[r][0] = 0.f; acc[r][1] = 0.f; }
    for (int k0 = 0; k0 < HID; k0 += 4) {
      float2 w0 = *(const float2*)&Ws[(k0 + 0) * HID + c2];
      float2 w1 = *(const float2*)&Ws[(k0 + 1) * HID + c2];
      float2 w2 = *(const float2*)&Ws[(k0 + 2) * HID + c2];
      float2 w3 = *(const float2*)&Ws[(k0 + 3) * HID + c2];
#pragma unroll
      for (int r = 0; r < 4; ++r) {
        float4 xv = *(const float4*)&xs[rq * 4 + r][k0];
        acc[r][0] = fmaf(xv.x, w0.x, acc[r][0]);
        acc[r][1] = fmaf(xv.x, w0.y, acc[r][1]);
        acc[r][0] = fmaf(xv.y, w1.x, acc[r][0]);
        acc[r][1] = fmaf(xv.y, w1.y, acc[r][1]);
        acc[r][0] = fmaf(xv.z, w2.x, acc[r][0]);
        acc[r][1] = fmaf(xv.z, w2.y, acc[r][1]);
        acc[r][0] = fmaf(xv.w, w3.x, acc[r][0]);
        acc[r][1] = fmaf(xv.w, w3.y, acc[r][1]);
      }
    }
#pragma unroll
    for (int r = 0; r < 4; ++r) {
      int row = r0 + rq * 4 + r;
      float ps = acc[r][0] * a_s0 + acc[r][1] * a_s1;
      float pd = acc[r][0] * a_d0 + acc[r][1] * a_d1;
#pragma unroll
      for (int msk = 1; msk < 16; msk <<= 1) {
        ps += __shfl_xor(ps, msk);
        pd += __shfl_xor(pd, msk);
      }
      if (row < N) {
        hbf[(size_t)row * 64 + pr] = pack_bf2(acc[r][0], acc[r][1]);
        if ((pr & 15) == 0) {
          as_out[row * 4 + (pr >> 4)] = ps;
          ad_out[row * 4 + (pr >> 4)] = pd;
        }
      }
    }
  }
}

// ---------------- per-dst agg+LN+ELU: TWO waves per dst ----------------
// block = 4 waves = 2 dsts. Wave half = wave&1 owns channels half*64..half*64+63.
// lane = g*8+qp : g = edge slot (8 edges/j-iter), qp = uint4 block within half-row.
__global__ __launch_bounds__(256) void k_gat_agg(const int* __restrict__ offs, const int* __restrict__ csr,
                                                 const float* __restrict__ as, const float* __restrict__ ad,
                                                 const uint4* __restrict__ hb, const float* __restrict__ bias,
                                                 const float* __restrict__ gam, const float* __restrict__ bet,
                                                 float* __restrict__ out, int ostride, int N) {
  __shared__ float lnA[4], lnB[4];
  int wave = threadIdx.x >> 6, lane = threadIdx.x & 63;
  int dst = blockIdx.x * 2 + (wave >> 1);
  int half = wave & 1;
  bool active = dst < N;
  int dcl = active ? dst : 0;
  int qp = lane & 7, g = lane >> 3;
  int q = half * 8 + qp;          // uint4 index in the 16-block row
  int head = q >> 2;              // 2 heads per wave
  float ad_h = ad[dcl * 4 + head];
  float p_self = __expf(leaky(as[dcl * 4 + head] + ad_h));
  float acc[8];
#pragma unroll
  for (int k = 0; k < 8; ++k) acc[k] = 0.f;
  float ssum = 0.f;
  int beg = active ? offs[dst] : 0, end = active ? offs[dst + 1] : 0;
  for (int base = beg; base < end; base += 64) {
    int idx = base + lane;
    int my = (idx < end) ? csr[idx] : 0;
    int cnt = min(64, end - base);
    for (int j = 0; j * 8 < cnt; ++j) {
      int sel = j * 8 + g;
      int s = __shfl(my, sel);
      bool v = sel < cnt;
      int ss = v ? s : 0;
      float p = v ? __expf(leaky(as[ss * 4 + head] + ad_h)) : 0.f;
      ssum += p;
      uint4 hr = hb[(size_t)ss * 16 + q];
#pragma unroll
      for (int k = 0; k < 4; ++k) {
        unsigned u = (&hr.x)[k];
        acc[2 * k]     = fmaf(p, __uint_as_float(u << 16), acc[2 * k]);
        acc[2 * k + 1] = fmaf(p, __uint_as_float(u & 0xffff0000u), acc[2 * k + 1]);
      }
    }
  }
  // combine the 8 edge groups (lane bits 3,4,5)
#pragma unroll
  for (int k = 0; k < 8; ++k) {
    acc[k] += __shfl_xor(acc[k], 8);
    acc[k] += __shfl_xor(acc[k], 16);
    acc[k] += __shfl_xor(acc[k], 32);
  }
  // per-head denom: reduce over bits {0,1,3,4,5}; bit2 = head selector. 4x dup -> *0.25
  float red = ssum;
  red += __shfl_xor(red, 1);
  red += __shfl_xor(red, 2);  // wait: bit1 is part of qp (same-head dup), bit2 selects head
  // correction: qp bits {0,1} are same-head dups; bit 2 flips head. Undo the bit-2 mix:
  // We must NOT include bit 2. Recompute cleanly below.
  red = ssum;
  red += __shfl_xor(red, 1);
  red += __shfl_xor(red, 2);
  // NOTE: bits 0,1 of qp are dup lanes within a head only if head = q>>2 = (half*8+qp)>>2
  // -> head flips at qp bit 2. Bits 0,1 are safe; bit 2 excluded; bits 3,4,5 are edge slots.
  red += __shfl_xor(red, 8);
  red += __shfl_xor(red, 16);
  red += __shfl_xor(red, 32);
  float denom = 0.25f * red + p_self;
  // self-loop
  uint4 hd = hb[(size_t)dcl * 16 + q];
#pragma unroll
  for (int k = 0; k < 4; ++k) {
    unsigned u = (&hd.x)[k];
    acc[2 * k]     = fmaf(p_self, __uint_as_float(u << 16), acc[2 * k]);
    acc[2 * k + 1] = fmaf(p_self, __uint_as_float(u & 0xffff0000u), acc[2 * k + 1]);
  }
  // normalize + bias
  int cb = q * 8;
  float inv = 1.f / denom;
  float val[8], part = 0.f;
#pragma unroll
  for (int k = 0; k < 8; ++k) {
    val[k] = acc[k] * inv + bias[cb + k];
    part += val[k];
  }
  // wave-partial LN sum over qp (bits 0,1,2), then cross-wave via LDS
  part += __shfl_xor(part, 1);
  part += __shfl_xor(part, 2);
  part += __shfl_xor(part, 4);
  if (lane == 0) lnA[wave] = active ? part : 0.f;
  __syncthreads();
  float mu = (lnA[wave ^ 1] + part) * (1.f / HID);
  float vpart = 0.f;
#pragma unroll
  for (int k = 0; k < 8; ++k) {
    val[k] -= mu;
    vpart += val[k] * val[k];
  }
  vpart += __shfl_xor(vpart, 1);
  vpart += __shfl_xor(vpart, 2);
  vpart += __shfl_xor(vpart, 4);
  if (lane == 0) lnB[wave] = active ? vpart : 0.f;
  __syncthreads();
  float rstd = rsqrtf((lnB[wave ^ 1] + vpart) * (1.f / HID) + LN_EPS);
  float y[8];
#pragma unroll
  for (int k = 0; k < 8; ++k) {
    float tv = val[k] * rstd * gam[cb + k] + bet[cb + k];
    y[k] = tv > 0.f ? tv : expm1f(tv);
  }
  if (active && g == 0) {
    *(float4*)&out[(size_t)dst * ostride + cb]     = make_float4(y[0], y[1], y[2], y[3]);
    *(float4*)&out[(size_t)dst * ostride + cb + 4] = make_float4(y[4], y[5], y[6], y[7]);
  }
}

// ---------------- per-graph mean readout (reads strided x) ----------------
__global__ __launch_bounds__(256) void k_graph_sum(const float* __restrict__ x, int xstride,
                                                   const int* __restrict__ bat,
                                                   float* __restrict__ gsum, float* __restrict__ gcnt, int N) {
  __shared__ float ls[NG * HID];
  __shared__ float lc[NG];
  for (int i = threadIdx.x; i < NG * HID; i += 256) ls[i] = 0.f;
  if (threadIdx.x < NG) lc[threadIdx.x] = 0.f;
  __syncthreads();
  int wave = threadIdx.x >> 6, lane = threadIdx.x & 63;
  for (int n = blockIdx.x * 4 + wave; n < N; n += gridDim.x * 4) {
    int b = bat[n];
    float2 v = *(const float2*)&x[(size_t)n * xstride + lane * 2];
    atomicAdd(&ls[b * HID + lane * 2], v.x);
    atomicAdd(&ls[b * HID + lane * 2 + 1], v.y);
    if (lane == 0) atomicAdd(&lc[b], 1.f);
  }
  __syncthreads();
  for (int i = threadIdx.x; i < NG * HID; i += 256) atomicAdd(&gsum[i], ls[i]);
  if (threadIdx.x < NG) atomicAdd(&gcnt[threadIdx.x], lc[threadIdx.x]);
}

// g-half of output
__global__ __launch_bounds__(256) void k_gout(const int* __restrict__ bat, const float* __restrict__ gsum,
                                              const float* __restrict__ gcnt, float* __restrict__ out, int N) {
  int total = N * 32;
  for (int idx = blockIdx.x * blockDim.x + threadIdx.x; idx < total; idx += gridDim.x * blockDim.x) {
    int n = idx >> 5, qq = idx & 31;
    int b = bat[n];
    float rin = 1.f / fmaxf(gcnt[b], 1.f);
    float4 gv = *(const float4*)&gsum[b * HID + qq * 4];
    *(float4*)&out[(size_t)n * 256 + 128 + qq * 4] =
        make_float4(gv.x * rin, gv.y * rin, gv.z * rin, gv.w * rin);
  }
}

extern "C" void kernel_launch(void* const* d_in, const int* in_sizes, int n_in,
                              void* d_out, int out_size, void* d_ws, size_t ws_size,
                              hipStream_t stream) {
  const float* x   = (const float*)d_in[0];
  const int*   ei  = (const int*)d_in[1];
  const int*   bat = (const int*)d_in[2];
  const float* W1  = (const float*)d_in[3];
  const float* as1 = (const float*)d_in[4];
  const float* ad1 = (const float*)d_in[5];
  const float* b1  = (const float*)d_in[6];
  const float* g1  = (const float*)d_in[7];
  const float* be1 = (const float*)d_in[8];
  const float* W2  = (const float*)d_in[9];
  const float* as2 = (const float*)d_in[10];
  const float* ad2 = (const float*)d_in[11];
  const float* b2  = (const float*)d_in[12];
  const float* g2  = (const float*)d_in[13];
  const float* be2 = (const float*)d_in[14];
  int N = in_sizes[0] / HID;
  int E = in_sizes[1] / 2;

  char* p = (char*)d_ws;
  auto alloc = [&](size_t bytes) {
    void* r = (void*)p;
    p += (bytes + 255) & ~(size_t)255;
    return r;
  };
  int*      deg  = (int*)alloc((size_t)N * 4);   // also fill cursor
  int*      offs = (int*)alloc((size_t)(N + 1) * 4);
  int       nsb  = (N + 1023) / 1024;
  int*      part = (int*)alloc((size_t)nsb * 4);
  int*      csr  = (int*)alloc((size_t)E * 4);
  unsigned* hbf  = (unsigned*)alloc((size_t)N * 64 * 4);   // bf16x2-packed h
  float*    asb  = (float*)alloc((size_t)N * 4 * 4);
  float*    adb  = (float*)alloc((size_t)N * 4 * 4);
  float*    gsum = (float*)alloc((size_t)NG * HID * 4);
  float*    gcnt = (float*)alloc((size_t)NG * 4);

  hipMemsetAsync(deg, 0, (size_t)N * 4, stream);
  hipMemsetAsync(gsum, 0, (size_t)NG * HID * 4, stream);
  hipMemsetAsync(gcnt, 0, (size_t)NG * 4, stream);

  int egrid = (E + 255) / 256;
  if (egrid > 2048) egrid = 2048;
  k_edge_count<<<egrid, 256, 0, stream>>>(ei, E, deg);
  k_scan_a<<<nsb, 1024, 0, stream>>>(deg, offs, part, N);
  k_scan_b<<<1, 1024, 0, stream>>>(part, nsb);
  k_scan_c<<<(N + 255) / 256, 256, 0, stream>>>(offs, part, N);
  hipMemsetAsync(deg, 0, (size_t)N * 4, stream);  // cursor
  k_edge_fill<<<egrid, 256, 0, stream>>>(ei, E, offs, deg, csr);

  int ntiles = (N + 31) / 32;
  int ggrid = ntiles < 512 ? ntiles : 512;
  int agrid = (N + 1) / 2;
  float* xhalf = (float*)d_out;  // layer outputs live in d_out's x-half (stride 256)

  k_gemm<<<ggrid, 512, 0, stream>>>(x, HID, W1, as1, ad1, hbf, asb, adb, N, ntiles);
  k_gat_agg<<<agrid, 256, 0, stream>>>(offs, csr, asb, adb, (const uint4*)hbf, b1, g1, be1,
                                       xhalf, 256, N);
  k_gemm<<<ggrid, 512, 0, stream>>>(xhalf, 256, W2, as2, ad2, hbf, asb, adb, N, ntiles);
  k_gat_agg<<<agrid, 256, 0, stream>>>(offs, csr, asb, adb, (const uint4*)hbf, b2, g2, be2,
                                       xhalf, 256, N);

  k_graph_sum<<<256, 256, 0, stream>>>(xhalf, 256, bat, gsum, gcnt, N);
  int ogrid = (N * 32 + 255) / 256;
  if (ogrid > 4096) ogrid = 4096;
  k_gout<<<ogrid, 256, 0, stream>>>(bat, gsum, gcnt, (float*)d_out, N);
}